// Round 4
// baseline (1403.087 us; speedup 1.0000x reference)
//
#include <hip/hip_runtime.h>
#include <hip/hip_bf16.h>

// LSTM-LL v4: rotation LDS swizzle (conflict-free b128 reads), 2 barriers/step
// (elem2 folded into next step's phase A; logits-MFMA shares h2 loads with g2).
// B=8192, T=128, E=128, V=128, L=2. 256 blocks x 512 thr, 32 rows/block.

typedef __bf16 bf16x8 __attribute__((ext_vector_type(8)));
typedef __bf16 bf16x4 __attribute__((ext_vector_type(4)));
typedef float  f32x4  __attribute__((ext_vector_type(4)));

#define LOG2E 1.4426950408889634f
#define LN2   0.6931471805599453f

static __device__ __bf16 g_emb1[128 * 512];  // [v][gate*128+e] = (emb[v]@Wih1^T + b1) * rowscale

__device__ __forceinline__ float frcp(float x) {
#if __has_builtin(__builtin_amdgcn_rcpf)
  return __builtin_amdgcn_rcpf(x);
#else
  return 1.0f / x;
#endif
}
__device__ __forceinline__ float fexp2(float x) {
#if __has_builtin(__builtin_amdgcn_exp2f)
  return __builtin_amdgcn_exp2f(x);
#else
  return exp2f(x);
#endif
}
__device__ __forceinline__ float flog2(float x) {
#if __has_builtin(__builtin_amdgcn_logf)
  return __builtin_amdgcn_logf(x);
#else
  return log2f(x);
#endif
}

// rotation swizzle for [*][128] bf16 LDS tiles: elem offset e -> (e + 8*(row&15)) & 127
__device__ __forceinline__ int hoff(int row, int e) {
  return row * 128 + ((e + ((row & 15) << 3)) & 127);
}

// emb1[v][col] = (dot(emb[v,:], Wih1[col,:]) + bih1[col] + bhh1[col]) * scale(gate)
__global__ void prep_emb1(const float* __restrict__ emb, const float* __restrict__ Wih,
                          const float* __restrict__ bih, const float* __restrict__ bhh) {
  __shared__ float embS[128 * 128];
  __shared__ float wS[32 * 128];
  const int tid = threadIdx.x, bc = blockIdx.x;
  for (int i = tid; i < 128 * 32; i += 512) ((f32x4*)embS)[i] = ((const f32x4*)emb)[i];
  for (int i = tid; i < 32 * 32; i += 512)
    ((f32x4*)wS)[i] = ((const f32x4*)(Wih + bc * 32 * 128))[i];
  __syncthreads();
  const int v = tid & 127, c0 = (tid >> 7) * 8;
  const int rot = v & 31;
#pragma unroll
  for (int j = 0; j < 8; ++j) {
    int c = c0 + j;
    float s = 0.f;
    for (int k = 0; k < 128; ++k) {
      int kk = (k + rot) & 127;
      s += embS[v * 128 + kk] * wS[c * 128 + kk];
    }
    int col = bc * 32 + c;
    float sc = ((col >> 7) == 2) ? 2.0f * LOG2E : LOG2E;
    g_emb1[v * 512 + col] = (__bf16)((s + bih[col] + bhh[col]) * sc);
  }
}

__global__ __launch_bounds__(512, 2) void lstm_ll(
    const float* __restrict__ state, const int* __restrict__ tokens,
    const float* __restrict__ W_ih, const float* __restrict__ W_hh,
    const float* __restrict__ b_ih, const float* __restrict__ b_hh,
    const float* __restrict__ W_out, const float* __restrict__ b_out,
    float* __restrict__ out) {
  __shared__ __align__(16) __bf16 wih2L[512 * 128];  // 128 KB resident
  __shared__ __align__(16) __bf16 h1L[2][32 * 128];  // 16 KB dbuf
  __shared__ __align__(16) __bf16 h2L[32 * 128];     // 8 KB single-buffered
  __shared__ unsigned char tokL[128][32];            // 4 KB [t][r]
  __shared__ float wsum[8][32];                      // 1 KB
  __shared__ float llL[32];

  const int tid  = threadIdx.x;
  const int w    = tid >> 6;
  const int lane = tid & 63;
  const int lr   = lane & 15;
  const int lh   = lane >> 4;
  const int b0   = blockIdx.x * 32;
  const int col  = w * 16 + lr;      // gate-row index (MFMA A-frag m = lr)
  const int koff = lh * 8;           // k offset within a 32-chunk
  const int e0   = w * 16 + lh * 4;  // lane's 4 hidden units in D-frags
  const float gscA[4] = {LOG2E, LOG2E, 2.0f * LOG2E, LOG2E};

  // ---- one-time staging ----
  for (int i = tid; i < 512 * 16; i += 512) {
    int row = i >> 4, e = (i & 15) * 8;
    const float* p = W_ih + 512 * 128 + row * 128 + e;
    float sc = gscA[row >> 7];
    f32x4 x0 = *(const f32x4*)p, x1 = *(const f32x4*)(p + 4);
    bf16x8 v;
#pragma unroll
    for (int j = 0; j < 4; ++j) { v[j] = (__bf16)(x0[j] * sc); v[4 + j] = (__bf16)(x1[j] * sc); }
    *(bf16x8*)(wih2L + hoff(row, e)) = v;
  }
  for (int i = tid; i < 32 * 128; i += 512) {
    int r = i & 31, t = i >> 5;
    tokL[t][r] = (unsigned char)tokens[(b0 + r) * 128 + t];
  }
  if (tid < 32) llL[tid] = 0.0f;

  auto ldw8s = [&](const float* p, float sc) -> bf16x8 {
    f32x4 x0 = *(const f32x4*)p, x1 = *(const f32x4*)(p + 4);
    bf16x8 v;
#pragma unroll
    for (int j = 0; j < 4; ++j) { v[j] = (__bf16)(x0[j] * sc); v[4 + j] = (__bf16)(x1[j] * sc); }
    return v;
  };

  bf16x8 whh1[4][4], whh2[4][4], woutF[4];
#pragma unroll
  for (int kc = 0; kc < 4; ++kc) {
#pragma unroll
    for (int gg = 0; gg < 4; ++gg) {
      whh1[kc][gg] = ldw8s(W_hh + (gg * 128 + col) * 128 + kc * 32 + koff, gscA[gg]);
      whh2[kc][gg] = ldw8s(W_hh + 512 * 128 + (gg * 128 + col) * 128 + kc * 32 + koff, gscA[gg]);
    }
    woutF[kc] = ldw8s(W_out + col * 128 + kc * 32 + koff, LOG2E);
  }
  f32x4 bias2v4[4], bo4;
#pragma unroll
  for (int gg = 0; gg < 4; ++gg)
#pragma unroll
    for (int j = 0; j < 4; ++j)
      bias2v4[gg][j] = (b_ih[512 + gg * 128 + e0 + j] + b_hh[512 + gg * 128 + e0 + j]) * gscA[gg];
#pragma unroll
  for (int j = 0; j < 4; ++j) bo4[j] = b_out[e0 + j] * LOG2E;

  float c1[2][4] = {}, c2[2][4] = {};

  // B-frag (n = batch) from rotation-swizzled [32][128] LDS tile
  auto ldB = [&](const __bf16* buf, int nf, int kc) -> bf16x8 {
    return *(const bf16x8*)(buf + hoff(nf * 16 + lr, kc * 32 + koff));
  };

  f32x4 acc[4][2];  // [gate][batch-frag], reused by L1 (A') and g2 (B)
  auto zacc = [&]() {
#pragma unroll
    for (int gg = 0; gg < 4; ++gg)
#pragma unroll
      for (int nf = 0; nf < 2; ++nf) acc[gg][nf] = f32x4{0.f, 0.f, 0.f, 0.f};
  };

  auto elem = [&](const f32x4* b4, float (&c)[2][4], __bf16* hout) {
#pragma unroll
    for (int nf = 0; nf < 2; ++nf) {
      bf16x4 hp;
#pragma unroll
      for (int j = 0; j < 4; ++j) {
        float gi = acc[0][nf][j] + b4[0][j];
        float gf = acc[1][nf][j] + b4[1][j];
        float gc = acc[2][nf][j] + b4[2][j];
        float go = acc[3][nf][j] + b4[3][j];
        float sf = frcp(1.f + fexp2(-gf));
        float si = frcp(1.f + fexp2(-gi));
        float tg = 1.f - 2.f * frcp(fexp2(gc) + 1.f);
        float cc = sf * c[nf][j] + si * tg;
        c[nf][j] = cc;
        float so = frcp(1.f + fexp2(-go));
        float tc = 1.f - 2.f * frcp(fexp2(2.f * LOG2E * cc) + 1.f);
        hp[j] = (__bf16)(so * tc);
      }
      int b = nf * 16 + lr;
      *(bf16x4*)(hout + hoff(b, e0)) = hp;
    }
  };
  const f32x4 zf4 = {0.f, 0.f, 0.f, 0.f};
  const f32x4 zb4[4] = {zf4, zf4, zf4, zf4};

  __syncthreads();  // staging complete

  bf16x4 gv[2][4];
  auto gather = [&](int t) {
#pragma unroll
    for (int nf = 0; nf < 2; ++nf) {
      int tk = (int)tokL[t][nf * 16 + lr];
      const __bf16* pp = g_emb1 + tk * 512 + e0;
#pragma unroll
      for (int gg = 0; gg < 4; ++gg) gv[nf][gg] = *(const bf16x4*)(pp + gg * 128);
    }
  };
  gather(0);

  // ---- init step (x = state, h = c = 0); h0_l1 -> h1L[1], h0_l2 -> h2L ----
  {
    zacc();
#pragma unroll
    for (int kc = 0; kc < 4; ++kc) {
      bf16x8 s0 = ldw8s(state + (size_t)(b0 + lr) * 128 + kc * 32 + koff, 1.0f);
      bf16x8 s1 = ldw8s(state + (size_t)(b0 + 16 + lr) * 128 + kc * 32 + koff, 1.0f);
#pragma unroll
      for (int gg = 0; gg < 4; ++gg) {
        bf16x8 a = ldw8s(W_ih + (gg * 128 + col) * 128 + kc * 32 + koff, gscA[gg]);
        acc[gg][0] = __builtin_amdgcn_mfma_f32_16x16x32_bf16(a, s0, acc[gg][0], 0, 0, 0);
        acc[gg][1] = __builtin_amdgcn_mfma_f32_16x16x32_bf16(a, s1, acc[gg][1], 0, 0, 0);
      }
    }
    f32x4 bias1v4[4];
#pragma unroll
    for (int gg = 0; gg < 4; ++gg)
#pragma unroll
      for (int j = 0; j < 4; ++j)
        bias1v4[gg][j] = (b_ih[gg * 128 + e0 + j] + b_hh[gg * 128 + e0 + j]) * gscA[gg];
    elem(bias1v4, c1, h1L[1]);
    __syncthreads();
    zacc();  // layer-2 init: Wih2 x h1 only (h2 = 0)
#pragma unroll
    for (int kc = 0; kc < 4; ++kc) {
      bf16x8 x0 = ldB(h1L[1], 0, kc), x1 = ldB(h1L[1], 1, kc);
#pragma unroll
      for (int gg = 0; gg < 4; ++gg) {
        bf16x8 a = *(const bf16x8*)(wih2L + hoff(gg * 128 + col, kc * 32 + koff));
        acc[gg][0] = __builtin_amdgcn_mfma_f32_16x16x32_bf16(a, x0, acc[gg][0], 0, 0, 0);
        acc[gg][1] = __builtin_amdgcn_mfma_f32_16x16x32_bf16(a, x1, acc[gg][1], 0, 0, 0);
      }
    }
    elem(bias2v4, c2, h2L);
    __syncthreads();
  }

  f32x4 lvA, lvB;  // log2-domain logits of step t-1, computed in B(t)

  // ---- main loop, 2 barriers/iter ----
  // A'(t): elem2(t-1) -> h2 | exp/wsum(t-2) | L1-MFMA(t)+gv+elem1(t) -> h1L[t&1]
  // B(t):  ll-update(t-2) | g2-MFMA(t) + logits-MFMA(t-1) sharing h2 loads | gather(t+1)
#pragma unroll 1
  for (int t = 0; t <= 128; ++t) {
    const bool doL1 = (t <= 126);
    const bool doE2 = (t >= 1) && (t <= 127);
    const bool doSM = (t >= 2);
    const bool doLG = (t >= 1) && (t <= 127);

    // -------- Phase A' --------
    if (doE2) elem(bias2v4, c2, h2L);  // consumes g2 acc from B(t-1)
    if (doSM) {
      float s0 = fexp2(lvA[0]) + fexp2(lvA[1]) + fexp2(lvA[2]) + fexp2(lvA[3]);
      float s1 = fexp2(lvB[0]) + fexp2(lvB[1]) + fexp2(lvB[2]) + fexp2(lvB[3]);
      s0 += __shfl_xor(s0, 16); s0 += __shfl_xor(s0, 32);
      s1 += __shfl_xor(s1, 16); s1 += __shfl_xor(s1, 32);
      if (lh == 0) { wsum[w][lr] = s0; wsum[w][16 + lr] = s1; }
    }
    if (doL1) {
      const __bf16* h1p = h1L[(t + 1) & 1];
      zacc();
#pragma unroll
      for (int kc = 0; kc < 4; ++kc) {
        bf16x8 p0 = ldB(h1p, 0, kc), p1 = ldB(h1p, 1, kc);
#pragma unroll
        for (int gg = 0; gg < 4; ++gg) {
          acc[gg][0] = __builtin_amdgcn_mfma_f32_16x16x32_bf16(whh1[kc][gg], p0, acc[gg][0], 0, 0, 0);
          acc[gg][1] = __builtin_amdgcn_mfma_f32_16x16x32_bf16(whh1[kc][gg], p1, acc[gg][1], 0, 0, 0);
        }
      }
#pragma unroll
      for (int nf = 0; nf < 2; ++nf)
#pragma unroll
        for (int gg = 0; gg < 4; ++gg)
#pragma unroll
          for (int j = 0; j < 4; ++j) acc[gg][nf][j] += (float)gv[nf][gg][j];
      elem(zb4, c1, h1L[t & 1]);
    }
    __syncthreads();  // BAR1

    // -------- Phase B --------
    if (doSM) {  // ll-update(t-2): must read lvA/lvB before logits overwrite
#pragma unroll
      for (int nf = 0; nf < 2; ++nf) {
        int r = nf * 16 + lr;
        int tgt = (int)tokL[t - 1][r];
        if ((tgt >> 4) == w && ((tgt >> 2) & 3) == lh) {
          int j = tgt & 3;
          const f32x4& lv = nf ? lvB : lvA;
          float lvs = (j & 2) ? ((j & 1) ? lv[3] : lv[2]) : ((j & 1) ? lv[1] : lv[0]);
          float S = 0.f;
#pragma unroll
          for (int ww = 0; ww < 8; ++ww) S += wsum[ww][r];
          llL[r] += lvs - flog2(S);
        }
      }
    }
    if (doL1 || doLG) {
      const __bf16* h1c = h1L[t & 1];
      f32x4 la0 = zf4, la1 = zf4;
      if (doL1) zacc();
#pragma unroll
      for (int kc = 0; kc < 4; ++kc) {
        bf16x8 y0 = ldB(h2L, 0, kc), y1 = ldB(h2L, 1, kc);
        if (doL1) {
          bf16x8 x0 = ldB(h1c, 0, kc), x1 = ldB(h1c, 1, kc);
#pragma unroll
          for (int gg = 0; gg < 4; ++gg) {
            bf16x8 a = *(const bf16x8*)(wih2L + hoff(gg * 128 + col, kc * 32 + koff));
            acc[gg][0] = __builtin_amdgcn_mfma_f32_16x16x32_bf16(a, x0, acc[gg][0], 0, 0, 0);
            acc[gg][1] = __builtin_amdgcn_mfma_f32_16x16x32_bf16(a, x1, acc[gg][1], 0, 0, 0);
            acc[gg][0] = __builtin_amdgcn_mfma_f32_16x16x32_bf16(whh2[kc][gg], y0, acc[gg][0], 0, 0, 0);
            acc[gg][1] = __builtin_amdgcn_mfma_f32_16x16x32_bf16(whh2[kc][gg], y1, acc[gg][1], 0, 0, 0);
          }
        }
        if (doLG) {
          la0 = __builtin_amdgcn_mfma_f32_16x16x32_bf16(woutF[kc], y0, la0, 0, 0, 0);
          la1 = __builtin_amdgcn_mfma_f32_16x16x32_bf16(woutF[kc], y1, la1, 0, 0, 0);
        }
      }
      if (doLG) { lvA = la0 + bo4; lvB = la1 + bo4; }
    }
    if (t <= 125) gather(t + 1);
    __syncthreads();  // BAR2
  }

  if (tid < 32) out[b0 + tid] = llL[tid] * LN2;
}

extern "C" void kernel_launch(void* const* d_in, const int* in_sizes, int n_in,
                              void* d_out, int out_size, void* d_ws, size_t ws_size,
                              hipStream_t stream) {
  const float* state  = (const float*)d_in[0];
  const int*   tokens = (const int*)d_in[1];
  const float* emb    = (const float*)d_in[2];
  const float* Wih    = (const float*)d_in[3];
  const float* Whh    = (const float*)d_in[4];
  const float* bih    = (const float*)d_in[5];
  const float* bhh    = (const float*)d_in[6];
  const float* Wout   = (const float*)d_in[7];
  const float* bout   = (const float*)d_in[8];
  float* out = (float*)d_out;

  prep_emb1<<<16, 512, 0, stream>>>(emb, Wih, bih, bhh);
  lstm_ll<<<256, 512, 0, stream>>>(state, tokens, Wih, Whh, bih, bhh, Wout, bout, out);
}